// Round 4
// baseline (4339.047 us; speedup 1.0000x reference)
//
#include <hip/hip_runtime.h>
#include <math.h>

namespace {

constexpr int kNU = 100000;
constexpr int kNI = 50000;
constexpr int kDIN = 64;
constexpr int kDH = 128;
constexpr int kDH2 = kDH / 2;          // u32 (bf16x2) per feature row
constexpr int kNNZ = 5000000;
constexpr float kSlope = 0.2f;
constexpr float kEps = 1e-5f;

constexpr int kNSeg = kNU + kNI;
constexpr int kScanTile = 2048;
constexpr int kScanBlocks = (kNSeg + kScanTile - 1) / kScanTile;

// Binned-build parameters
constexpr int kBktShift = 8;                          // 256 segs per bucket
constexpr int kNBkt = (kNSeg + 255) >> kBktShift;     // 586
constexpr int kP1Edges = 3072;                        // edges per p1 block
constexpr int kP1Rec = kP1Edges * 2;                  // 6144 records (48KB LDS)

struct alignas(8) Edge { int idx; float val; };

// ---- bf16x2 <-> f32 helpers (RNE pack) ----
__device__ inline float2 bf2f(uint p) {
  return make_float2(__uint_as_float(p << 16),
                     __uint_as_float(p & 0xffff0000u));
}
__device__ inline uint f2bf1(float f) {
  const uint a = __float_as_uint(f);
  return (a + 0x7fffu + ((a >> 16) & 1u)) >> 16;
}
__device__ inline uint f2bf(float2 v) {
  return f2bf1(v.x) | (f2bf1(v.y) << 16);
}

// ---------------------------------------------------------------------------
// Input FC -> bf16 state buffers + f32 accumulator (d_out)
// ---------------------------------------------------------------------------
__global__ __launch_bounds__(128) void fc_in_kernel(
    const float* __restrict__ emb, const float* __restrict__ wu,
    const float* __restrict__ bu, const float* __restrict__ wi,
    const float* __restrict__ bi, uint* __restrict__ ubuf,
    uint* __restrict__ ibuf, float* __restrict__ out) {
  const int n = blockIdx.x;
  const int d = threadIdx.x;
  __shared__ float e[kDIN];
  __shared__ float sh[kDH];
  if (d < kDIN) e[d] = emb[(size_t)n * kDIN + d];
  __syncthreads();
  const float* W;
  const float* B;
  uint* dst;
  int nl;
  if (n < kNU) { W = wu; B = bu; dst = ubuf; nl = n; }
  else         { W = wi; B = bi; dst = ibuf; nl = n - kNU; }
  float s = B[d];
  const float* wr = W + (size_t)d * kDIN;
#pragma unroll
  for (int k = 0; k < kDIN; ++k) s = fmaf(e[k], wr[k], s);
  s = s > 0.f ? s : kSlope * s;
  sh[d] = s;
  out[(size_t)n * kDH + d] = s;
  __syncthreads();
  if (d < kDH2)
    dst[(size_t)nl * kDH2 + d] = f2bf(make_float2(sh[2 * d], sh[2 * d + 1]));
}

// ---------------------------------------------------------------------------
// Adjacency build: histogram -> scan -> LDS-binned two-pass placement
// ---------------------------------------------------------------------------
__global__ __launch_bounds__(256) void hist_kernel(
    const int* __restrict__ rows, const int* __restrict__ cols,
    int* __restrict__ cnt) {
  const int e = blockIdx.x * 256 + threadIdx.x;
  if (e >= kNNZ) return;
  atomicAdd(&cnt[rows[e]], 1);
  atomicAdd(&cnt[kNU + cols[e]], 1);
}

__global__ __launch_bounds__(256) void scan_partial_kernel(
    const int* __restrict__ in, int* __restrict__ out, int* __restrict__ bsum,
    int N) {
  __shared__ int sdata[256];
  const int tid = threadIdx.x;
  const int base = blockIdx.x * kScanTile + tid * 8;
  int v[8];
  int s = 0;
#pragma unroll
  for (int j = 0; j < 8; ++j) {
    v[j] = (base + j < N) ? in[base + j] : 0;
    s += v[j];
  }
  sdata[tid] = s;
  __syncthreads();
#pragma unroll
  for (int off = 1; off < 256; off <<= 1) {
    int t = (tid >= off) ? sdata[tid - off] : 0;
    __syncthreads();
    sdata[tid] += t;
    __syncthreads();
  }
  int run = sdata[tid] - s;
#pragma unroll
  for (int j = 0; j < 8; ++j) {
    if (base + j < N) out[base + j] = run;
    run += v[j];
  }
  if (tid == 255) bsum[blockIdx.x] = sdata[255];
}

__global__ __launch_bounds__(256) void scan_bsums_kernel(int* __restrict__ bsum,
                                                         int M) {
  __shared__ int sd[256];
  const int tid = threadIdx.x;
  const int v = (tid < M) ? bsum[tid] : 0;
  sd[tid] = v;
  __syncthreads();
#pragma unroll
  for (int off = 1; off < 256; off <<= 1) {
    int t = (tid >= off) ? sd[tid - off] : 0;
    __syncthreads();
    sd[tid] += t;
    __syncthreads();
  }
  if (tid < M) bsum[tid] = sd[tid] - v;
}

__global__ __launch_bounds__(256) void scan_add_kernel(
    int* __restrict__ out, const int* __restrict__ bsum, int N) {
  const int i = blockIdx.x * 256 + threadIdx.x;
  if (i < N) out[i] += bsum[i / kScanTile];
  if (i == 0) out[N] = 2 * kNNZ;
}

__global__ __launch_bounds__(256) void init_gcur_kernel(
    int* __restrict__ gcur, const int* __restrict__ ptr) {
  const int b = blockIdx.x * 256 + threadIdx.x;
  if (b < kNBkt) gcur[b] = ptr[b << kBktShift];
}

// Pass 1: block-local counting sort of 6144 records by bucket, then dense
// per-bucket append to the bucket's staging region (one XCD per flush chunk).
__global__ __launch_bounds__(256) void p1_bin_kernel(
    const int* __restrict__ rows, const int* __restrict__ cols,
    const float* __restrict__ vals, int* __restrict__ gcur,
    uint2* __restrict__ staging) {
  __shared__ uint2 rec[kP1Rec];       // 48 KB
  __shared__ int offs[kNBkt + 1];     // exclusive offsets (after scan)
  __shared__ int slot[kNBkt];         // running insert cursors
  __shared__ int sc[256];
  const int tid = threadIdx.x;
  const int e0 = blockIdx.x * kP1Edges;
  const int ne = min(kP1Edges, kNNZ - e0);

  for (int b = tid; b <= kNBkt; b += 256) offs[b] = 0;
  __syncthreads();
  // Phase A: count records per bucket
  for (int j = tid; j < ne; j += 256) {
    const int r = rows[e0 + j];
    const int c = cols[e0 + j];
    atomicAdd(&offs[r >> kBktShift], 1);
    atomicAdd(&offs[(kNU + c) >> kBktShift], 1);
  }
  __syncthreads();
  // Phase B: exclusive scan over kNBkt buckets (3 per thread + block scan)
  const int base = tid * 3;
  int v0 = 0, v1 = 0, v2 = 0;
  if (base + 0 < kNBkt) v0 = offs[base + 0];
  if (base + 1 < kNBkt) v1 = offs[base + 1];
  if (base + 2 < kNBkt) v2 = offs[base + 2];
  const int tsum = v0 + v1 + v2;
  sc[tid] = tsum;
  __syncthreads();
#pragma unroll
  for (int off = 1; off < 256; off <<= 1) {
    int t = (tid >= off) ? sc[tid - off] : 0;
    __syncthreads();
    sc[tid] += t;
    __syncthreads();
  }
  const int run = sc[tid] - tsum;
  __syncthreads();
  if (base + 0 < kNBkt) { offs[base + 0] = run;           slot[base + 0] = run; }
  if (base + 1 < kNBkt) { offs[base + 1] = run + v0;      slot[base + 1] = run + v0; }
  if (base + 2 < kNBkt) { offs[base + 2] = run + v0 + v1; slot[base + 2] = run + v0 + v1; }
  if (tid == 255) offs[kNBkt] = sc[255];
  __syncthreads();
  // Phase C: scatter records into LDS, grouped by bucket
  for (int j = tid; j < ne; j += 256) {
    const int r = rows[e0 + j];
    const int c = cols[e0 + j];
    const uint vb = __float_as_uint(vals[e0 + j]);
    // CSR record: seg=r, gather idx=c
    int b = r >> kBktShift;
    int p = atomicAdd(&slot[b], 1);
    rec[p] = make_uint2(((uint)c << 8) | (uint)(r & 255), vb);
    // CSC record: seg=kNU+c, gather idx=r
    const int s2 = kNU + c;
    b = s2 >> kBktShift;
    p = atomicAdd(&slot[b], 1);
    rec[p] = make_uint2(((uint)r << 8) | (uint)(s2 & 255), vb);
  }
  __syncthreads();
  // Phase D: per-bucket dense flush (wave per bucket, strided)
  const int wid = tid >> 6;
  const int lane = tid & 63;
  for (int b = wid; b < kNBkt; b += 4) {
    const int o = offs[b];
    const int csize = offs[b + 1] - o;
    if (csize == 0) continue;
    int gb;
    if (lane == 0) gb = atomicAdd(&gcur[b], csize);
    gb = __shfl(gb, 0, 64);
    for (int r = lane; r < csize; r += 64) staging[gb + r] = rec[o + r];
  }
}

// Pass 2: one block per bucket; sequential read of staging region, exact
// position via LDS per-seg cursor, write final edge record (single-XCD window).
__global__ __launch_bounds__(256) void p2_place_kernel(
    const uint2* __restrict__ staging, const int* __restrict__ ptr,
    Edge* __restrict__ edges) {
  __shared__ int curr[256];
  const int b = blockIdx.x;
  const int seg0 = b << kBktShift;
  const int segend = min(seg0 + 256, kNSeg);
  const int tid = threadIdx.x;
  if (seg0 + tid < segend) curr[tid] = ptr[seg0 + tid];
  __syncthreads();
  const int rbeg = ptr[seg0];
  const int rend = ptr[segend];
  for (int r = rbeg + tid; r < rend; r += 256) {
    const uint2 rc = staging[r];
    const int sl = rc.x & 255u;
    const int idx = rc.x >> 8;
    const int p = atomicAdd(&curr[sl], 1);
    *(int2*)&edges[p] = make_int2(idx, (int)rc.y);
  }
}

// ---------------------------------------------------------------------------
// Gather SpMM (bf16 src/dst, f32 accumulate). One wave per output row,
// one bf16x2 word (2 feats) per lane. Dual variant shares one edge traversal.
// ---------------------------------------------------------------------------
__global__ __launch_bounds__(256) void spmm_g1_kernel(
    uint* __restrict__ dst, const uint* __restrict__ src,
    const int* __restrict__ ptr, const Edge* __restrict__ edges, int N) {
  const int wid = threadIdx.x >> 6;
  const int lane = threadIdx.x & 63;
  const int n = blockIdx.x * 4 + wid;
  if (n >= N) return;
  int e = ptr[n];
  const int e1 = ptr[n + 1];
  float2 acc = make_float2(0.f, 0.f);
  for (; e + 4 <= e1; e += 4) {
    const Edge r0 = edges[e + 0];
    const Edge r1 = edges[e + 1];
    const Edge r2 = edges[e + 2];
    const Edge r3 = edges[e + 3];
    const float2 s0 = bf2f(src[(size_t)r0.idx * kDH2 + lane]);
    const float2 s1 = bf2f(src[(size_t)r1.idx * kDH2 + lane]);
    const float2 s2 = bf2f(src[(size_t)r2.idx * kDH2 + lane]);
    const float2 s3 = bf2f(src[(size_t)r3.idx * kDH2 + lane]);
    acc.x = fmaf(r0.val, s0.x, acc.x); acc.y = fmaf(r0.val, s0.y, acc.y);
    acc.x = fmaf(r1.val, s1.x, acc.x); acc.y = fmaf(r1.val, s1.y, acc.y);
    acc.x = fmaf(r2.val, s2.x, acc.x); acc.y = fmaf(r2.val, s2.y, acc.y);
    acc.x = fmaf(r3.val, s3.x, acc.x); acc.y = fmaf(r3.val, s3.y, acc.y);
  }
  for (; e < e1; ++e) {
    const Edge r = edges[e];
    const float2 s = bf2f(src[(size_t)r.idx * kDH2 + lane]);
    acc.x = fmaf(r.val, s.x, acc.x);
    acc.y = fmaf(r.val, s.y, acc.y);
  }
  dst[(size_t)n * kDH2 + lane] = f2bf(acc);
}

__global__ __launch_bounds__(256) void spmm_g2_kernel(
    uint* __restrict__ dstA, const uint* __restrict__ srcA,
    uint* __restrict__ dstB, const uint* __restrict__ srcB,
    const int* __restrict__ ptr, const Edge* __restrict__ edges, int N) {
  const int wid = threadIdx.x >> 6;
  const int lane = threadIdx.x & 63;
  const int n = blockIdx.x * 4 + wid;
  if (n >= N) return;
  int e = ptr[n];
  const int e1 = ptr[n + 1];
  float2 aA = make_float2(0.f, 0.f);
  float2 aB = make_float2(0.f, 0.f);
  for (; e + 4 <= e1; e += 4) {
    const Edge r0 = edges[e + 0];
    const Edge r1 = edges[e + 1];
    const Edge r2 = edges[e + 2];
    const Edge r3 = edges[e + 3];
    const float2 a0 = bf2f(srcA[(size_t)r0.idx * kDH2 + lane]);
    const float2 b0 = bf2f(srcB[(size_t)r0.idx * kDH2 + lane]);
    const float2 a1 = bf2f(srcA[(size_t)r1.idx * kDH2 + lane]);
    const float2 b1 = bf2f(srcB[(size_t)r1.idx * kDH2 + lane]);
    const float2 a2 = bf2f(srcA[(size_t)r2.idx * kDH2 + lane]);
    const float2 b2 = bf2f(srcB[(size_t)r2.idx * kDH2 + lane]);
    const float2 a3 = bf2f(srcA[(size_t)r3.idx * kDH2 + lane]);
    const float2 b3 = bf2f(srcB[(size_t)r3.idx * kDH2 + lane]);
    aA.x = fmaf(r0.val, a0.x, aA.x); aA.y = fmaf(r0.val, a0.y, aA.y);
    aB.x = fmaf(r0.val, b0.x, aB.x); aB.y = fmaf(r0.val, b0.y, aB.y);
    aA.x = fmaf(r1.val, a1.x, aA.x); aA.y = fmaf(r1.val, a1.y, aA.y);
    aB.x = fmaf(r1.val, b1.x, aB.x); aB.y = fmaf(r1.val, b1.y, aB.y);
    aA.x = fmaf(r2.val, a2.x, aA.x); aA.y = fmaf(r2.val, a2.y, aA.y);
    aB.x = fmaf(r2.val, b2.x, aB.x); aB.y = fmaf(r2.val, b2.y, aB.y);
    aA.x = fmaf(r3.val, a3.x, aA.x); aA.y = fmaf(r3.val, a3.y, aA.y);
    aB.x = fmaf(r3.val, b3.x, aB.x); aB.y = fmaf(r3.val, b3.y, aB.y);
  }
  for (; e < e1; ++e) {
    const Edge r = edges[e];
    const float2 a = bf2f(srcA[(size_t)r.idx * kDH2 + lane]);
    const float2 b = bf2f(srcB[(size_t)r.idx * kDH2 + lane]);
    aA.x = fmaf(r.val, a.x, aA.x); aA.y = fmaf(r.val, a.y, aA.y);
    aB.x = fmaf(r.val, b.x, aB.x); aB.y = fmaf(r.val, b.y, aB.y);
  }
  dstA[(size_t)n * kDH2 + lane] = f2bf(aA);
  dstB[(size_t)n * kDH2 + lane] = f2bf(aB);
}

// ---------------------------------------------------------------------------
// Fused FC (bias-free) + LayerNorm, bf16 in/out, f32 math.
// ---------------------------------------------------------------------------
constexpr int kFclnRows = 8;
constexpr int kWPad = 132;

__global__ __launch_bounds__(256) void fcln_kernel(
    const uint* __restrict__ X, const float* __restrict__ W,
    const float* __restrict__ g, const float* __restrict__ b,
    uint* __restrict__ out, int N) {
  __shared__ float Wt[kDH * kWPad];
  __shared__ float Xl[kFclnRows][kDH];
  const int tid = threadIdx.x;
  for (int idx = tid; idx < kDH * kDH; idx += 256) {
    const int d = idx >> 7, k = idx & 127;
    Wt[k * kWPad + d] = W[idx];
  }
  const int row0 = blockIdx.x * kFclnRows;
  const int r = tid >> 5;
  const int l = tid & 31;
  {
    const int n = row0 + r;
    uint2 xv = make_uint2(0u, 0u);
    if (n < N) xv = *(const uint2*)(X + (size_t)n * kDH2 + l * 2);
    const float2 p0 = bf2f(xv.x);
    const float2 p1 = bf2f(xv.y);
    Xl[r][l * 4 + 0] = p0.x;
    Xl[r][l * 4 + 1] = p0.y;
    Xl[r][l * 4 + 2] = p1.x;
    Xl[r][l * 4 + 3] = p1.y;
  }
  __syncthreads();
  float4 acc = make_float4(0.f, 0.f, 0.f, 0.f);
  const int d0 = l * 4;
#pragma unroll 4
  for (int k = 0; k < kDH; ++k) {
    const float x = Xl[r][k];
    const float4 w = *(const float4*)(&Wt[k * kWPad + d0]);
    acc.x = fmaf(x, w.x, acc.x);
    acc.y = fmaf(x, w.y, acc.y);
    acc.z = fmaf(x, w.z, acc.z);
    acc.w = fmaf(x, w.w, acc.w);
  }
  float s = acc.x + acc.y + acc.z + acc.w;
  float sq = acc.x * acc.x + acc.y * acc.y + acc.z * acc.z + acc.w * acc.w;
#pragma unroll
  for (int m = 16; m >= 1; m >>= 1) {
    s += __shfl_xor(s, m, 32);
    sq += __shfl_xor(sq, m, 32);
  }
  const float mu = s * (1.f / kDH);
  const float var = sq * (1.f / kDH) - mu * mu;
  const float rs = 1.f / sqrtf(var + kEps);
  const int n = row0 + r;
  if (n < N) {
    const float4 gg = *(const float4*)(g + d0);
    const float4 bb = *(const float4*)(b + d0);
    float2 o0, o1;
    o0.x = (acc.x - mu) * rs * gg.x + bb.x;
    o0.y = (acc.y - mu) * rs * gg.y + bb.y;
    o1.x = (acc.z - mu) * rs * gg.z + bb.z;
    o1.y = (acc.w - mu) * rs * gg.w + bb.w;
    *(uint2*)(out + (size_t)n * kDH2 + l * 2) = make_uint2(f2bf(o0), f2bf(o1));
  }
}

// ---------------------------------------------------------------------------
// h = leaky(LN(T)*g+b); upd(bf16) += h; acc(f32, d_out) += h
// ---------------------------------------------------------------------------
__global__ __launch_bounds__(256) void leaky_ln_kernel(
    const uint* __restrict__ T, const float* __restrict__ g,
    const float* __restrict__ b, uint* __restrict__ upd,
    float* __restrict__ acc, int N) {
  const int wid = threadIdx.x >> 6;
  const int lane = threadIdx.x & 63;
  const int n = blockIdx.x * 4 + wid;
  if (n >= N) return;
  const float2 v = bf2f(T[(size_t)n * kDH2 + lane]);
  float s = v.x + v.y;
  float sq = v.x * v.x + v.y * v.y;
#pragma unroll
  for (int m = 32; m >= 1; m >>= 1) {
    s += __shfl_xor(s, m, 64);
    sq += __shfl_xor(sq, m, 64);
  }
  const float mu = s * (1.f / kDH);
  const float var = sq * (1.f / kDH) - mu * mu;
  const float rs = 1.f / sqrtf(var + kEps);
  const int d = lane * 2;
  const float2 gg = *(const float2*)(g + d);
  const float2 bb = *(const float2*)(b + d);
  float hx = (v.x - mu) * rs * gg.x + bb.x;
  float hy = (v.y - mu) * rs * gg.y + bb.y;
  hx = hx > 0.f ? hx : kSlope * hx;
  hy = hy > 0.f ? hy : kSlope * hy;
  float2 uv = bf2f(upd[(size_t)n * kDH2 + lane]);
  uv.x += hx;
  uv.y += hy;
  upd[(size_t)n * kDH2 + lane] = f2bf(uv);
  float2 av = *(const float2*)(acc + (size_t)n * kDH + d);
  av.x += hx;
  av.y += hy;
  *(float2*)(acc + (size_t)n * kDH + d) = av;
}

__global__ __launch_bounds__(256) void scale_kernel(float* __restrict__ p,
                                                    float sc, int n4) {
  const int gid = blockIdx.x * 256 + threadIdx.x;
  if (gid < n4) {
    float4 v = ((float4*)p)[gid];
    v.x *= sc; v.y *= sc; v.z *= sc; v.w *= sc;
    ((float4*)p)[gid] = v;
  }
}

}  // namespace

extern "C" void kernel_launch(void* const* d_in, const int* in_sizes, int n_in,
                              void* d_out, int out_size, void* d_ws,
                              size_t ws_size, hipStream_t stream) {
  const float* emb    = (const float*)d_in[0];
  const float* fc_u_w = (const float*)d_in[1];
  const float* fc_u_b = (const float*)d_in[2];
  const float* fc_i_w = (const float*)d_in[3];
  const float* fc_i_b = (const float*)d_in[4];
  const float* vals   = (const float*)d_in[5];
  const float* Wu     = (const float*)d_in[6];
  const float* ln1g_u = (const float*)d_in[7];
  const float* ln1b_u = (const float*)d_in[8];
  const float* ln2g_u = (const float*)d_in[9];
  const float* ln2b_u = (const float*)d_in[10];
  const float* Wi     = (const float*)d_in[11];
  const float* ln1g_i = (const float*)d_in[12];
  const float* ln1b_i = (const float*)d_in[13];
  const float* ln2g_i = (const float*)d_in[14];
  const float* ln2b_i = (const float*)d_in[15];
  const int*   rows   = (const int*)d_in[16];
  const int*   cols   = (const int*)d_in[17];
  float* out = (float*)d_out;

  // Workspace: [bufU|bufI|P|Q|R] (115.2MB, also aliased by 80MB staging during
  // build) | edges[2*NNZ] | cnt | ptr | bsum | gcur
  uint* bufU = (uint*)d_ws;
  uint* bufI = bufU + (size_t)kNU * kDH2;
  uint* P    = bufI + (size_t)kNI * kDH2;
  uint* Q    = P + (size_t)kNU * kDH2;
  uint* R    = Q + (size_t)kNU * kDH2;
  uint2* staging = (uint2*)d_ws;  // build-phase alias of feature region
  Edge* edges = (Edge*)(R + (size_t)kNU * kDH2);
  int*  cnt  = (int*)(edges + (size_t)2 * kNNZ);
  int*  ptr  = cnt + kNSeg;           // kNSeg+1
  int*  bsum = ptr + kNSeg + 1;       // kScanBlocks
  int*  gcur = bsum + kScanBlocks;    // kNBkt

  const int egrid = (kNNZ + 255) / 256;
  const int gridU = (kNU + 3) / 4;
  const int gridI = (kNI + 3) / 4;
  const int fgridU = (kNU + kFclnRows - 1) / kFclnRows;
  const int fgridI = (kNI + kFclnRows - 1) / kFclnRows;

  // ---- adjacency build ----
  hipMemsetAsync(cnt, 0, (size_t)kNSeg * sizeof(int), stream);
  hist_kernel<<<egrid, 256, 0, stream>>>(rows, cols, cnt);
  scan_partial_kernel<<<kScanBlocks, 256, 0, stream>>>(cnt, ptr, bsum, kNSeg);
  scan_bsums_kernel<<<1, 256, 0, stream>>>(bsum, kScanBlocks);
  scan_add_kernel<<<(kNSeg + 255) / 256, 256, 0, stream>>>(ptr, bsum, kNSeg);
  init_gcur_kernel<<<(kNBkt + 255) / 256, 256, 0, stream>>>(gcur, ptr);
  p1_bin_kernel<<<(kNNZ + kP1Edges - 1) / kP1Edges, 256, 0, stream>>>(
      rows, cols, vals, gcur, staging);
  p2_place_kernel<<<kNBkt, 256, 0, stream>>>(staging, ptr, edges);

  // ---- input FC (after build: feature buffers alias staging) ----
  fc_in_kernel<<<kNU + kNI, 128, 0, stream>>>(emb, fc_u_w, fc_u_b, fc_i_w,
                                              fc_i_b, bufU, bufI, out);

  // ---- layer 0 ----
  spmm_g1_kernel<<<gridI, 256, 0, stream>>>(P, bufU, ptr + kNU, edges, kNI);
  fcln_kernel<<<fgridI, 256, 0, stream>>>(P, Wu, ln1g_u, ln1b_u, Q, kNI);
  spmm_g2_kernel<<<gridU, 256, 0, stream>>>(P, Q, R, bufI, ptr, edges, kNU);
  leaky_ln_kernel<<<gridU, 256, 0, stream>>>(P, ln2g_u, ln2b_u, bufU, out, kNU);
  fcln_kernel<<<fgridU, 256, 0, stream>>>(R, Wi, ln1g_i, ln1b_i, Q, kNU);
  spmm_g2_kernel<<<gridI, 256, 0, stream>>>(P, Q, R, bufU, ptr + kNU, edges,
                                            kNI);
  leaky_ln_kernel<<<gridI, 256, 0, stream>>>(P, ln2g_i, ln2b_i, bufI,
                                             out + (size_t)kNU * kDH, kNI);
  // ---- layer 1 ----
  fcln_kernel<<<fgridI, 256, 0, stream>>>(R, Wu + kDH * kDH, ln1g_u + kDH,
                                          ln1b_u + kDH, Q, kNI);
  spmm_g2_kernel<<<gridU, 256, 0, stream>>>(P, Q, R, bufI, ptr, edges, kNU);
  leaky_ln_kernel<<<gridU, 256, 0, stream>>>(P, ln2g_u + kDH, ln2b_u + kDH,
                                             bufU, out, kNU);
  fcln_kernel<<<fgridU, 256, 0, stream>>>(R, Wi + kDH * kDH, ln1g_i + kDH,
                                          ln1b_i + kDH, Q, kNU);
  spmm_g1_kernel<<<gridI, 256, 0, stream>>>(P, Q, ptr + kNU, edges, kNI);
  leaky_ln_kernel<<<gridI, 256, 0, stream>>>(P, ln2g_i + kDH, ln2b_i + kDH,
                                             bufI, out + (size_t)kNU * kDH,
                                             kNI);

  const int n4 = (kNU + kNI) * kDH / 4;
  scale_kernel<<<(n4 + 255) / 256, 256, 0, stream>>>(out, 1.f / 3.f, n4);
}

// Round 5
// 3457.387 us; speedup vs baseline: 1.2550x; 1.2550x over previous
//
#include <hip/hip_runtime.h>
#include <math.h>

namespace {

constexpr int kNU = 100000;
constexpr int kNI = 50000;
constexpr int kDIN = 64;
constexpr int kDH = 128;
constexpr int kDH2 = kDH / 2;          // u32 (bf16x2) per feature row
constexpr int kNNZ = 5000000;
constexpr float kSlope = 0.2f;
constexpr float kEps = 1e-5f;

constexpr int kNSeg = kNU + kNI;
constexpr int kScanTile = 2048;
constexpr int kScanBlocks = (kNSeg + kScanTile - 1) / kScanTile;

struct alignas(8) Edge { int idx; float val; };

// ---- bf16x2 <-> f32 helpers (RNE pack) ----
__device__ inline float2 bf2f(uint p) {
  return make_float2(__uint_as_float(p << 16),
                     __uint_as_float(p & 0xffff0000u));
}
__device__ inline uint f2bf1(float f) {
  const uint a = __float_as_uint(f);
  return (a + 0x7fffu + ((a >> 16) & 1u)) >> 16;
}
__device__ inline uint f2bf(float2 v) {
  return f2bf1(v.x) | (f2bf1(v.y) << 16);
}

__device__ inline void fma8(float* acc, uint4 s, float v) {
  float2 p;
  p = bf2f(s.x); acc[0] = fmaf(v, p.x, acc[0]); acc[1] = fmaf(v, p.y, acc[1]);
  p = bf2f(s.y); acc[2] = fmaf(v, p.x, acc[2]); acc[3] = fmaf(v, p.y, acc[3]);
  p = bf2f(s.z); acc[4] = fmaf(v, p.x, acc[4]); acc[5] = fmaf(v, p.y, acc[5]);
  p = bf2f(s.w); acc[6] = fmaf(v, p.x, acc[6]); acc[7] = fmaf(v, p.y, acc[7]);
}

__device__ inline uint4 pack8(const float* acc) {
  uint4 o;
  o.x = f2bf(make_float2(acc[0], acc[1]));
  o.y = f2bf(make_float2(acc[2], acc[3]));
  o.z = f2bf(make_float2(acc[4], acc[5]));
  o.w = f2bf(make_float2(acc[6], acc[7]));
  return o;
}

// ---------------------------------------------------------------------------
// Input FC -> bf16 state buffers + f32 accumulator (d_out)
// ---------------------------------------------------------------------------
__global__ __launch_bounds__(128) void fc_in_kernel(
    const float* __restrict__ emb, const float* __restrict__ wu,
    const float* __restrict__ bu, const float* __restrict__ wi,
    const float* __restrict__ bi, uint* __restrict__ ubuf,
    uint* __restrict__ ibuf, float* __restrict__ out) {
  const int n = blockIdx.x;
  const int d = threadIdx.x;
  __shared__ float e[kDIN];
  __shared__ float sh[kDH];
  if (d < kDIN) e[d] = emb[(size_t)n * kDIN + d];
  __syncthreads();
  const float* W;
  const float* B;
  uint* dst;
  int nl;
  if (n < kNU) { W = wu; B = bu; dst = ubuf; nl = n; }
  else         { W = wi; B = bi; dst = ibuf; nl = n - kNU; }
  float s = B[d];
  const float* wr = W + (size_t)d * kDIN;
#pragma unroll
  for (int k = 0; k < kDIN; ++k) s = fmaf(e[k], wr[k], s);
  s = s > 0.f ? s : kSlope * s;
  sh[d] = s;
  out[(size_t)n * kDH + d] = s;
  __syncthreads();
  if (d < kDH2)
    dst[(size_t)nl * kDH2 + d] = f2bf(make_float2(sh[2 * d], sh[2 * d + 1]));
}

// ---------------------------------------------------------------------------
// Adjacency build (histogram -> scan -> scatter), R2-proven version
// ---------------------------------------------------------------------------
__global__ __launch_bounds__(256) void hist_kernel(
    const int* __restrict__ rows, const int* __restrict__ cols,
    int* __restrict__ cnt) {
  const int e = blockIdx.x * 256 + threadIdx.x;
  if (e >= kNNZ) return;
  atomicAdd(&cnt[rows[e]], 1);
  atomicAdd(&cnt[kNU + cols[e]], 1);
}

__global__ __launch_bounds__(256) void scan_partial_kernel(
    const int* __restrict__ in, int* __restrict__ out, int* __restrict__ bsum,
    int N) {
  __shared__ int sdata[256];
  const int tid = threadIdx.x;
  const int base = blockIdx.x * kScanTile + tid * 8;
  int v[8];
  int s = 0;
#pragma unroll
  for (int j = 0; j < 8; ++j) {
    v[j] = (base + j < N) ? in[base + j] : 0;
    s += v[j];
  }
  sdata[tid] = s;
  __syncthreads();
#pragma unroll
  for (int off = 1; off < 256; off <<= 1) {
    int t = (tid >= off) ? sdata[tid - off] : 0;
    __syncthreads();
    sdata[tid] += t;
    __syncthreads();
  }
  int run = sdata[tid] - s;
#pragma unroll
  for (int j = 0; j < 8; ++j) {
    if (base + j < N) out[base + j] = run;
    run += v[j];
  }
  if (tid == 255) bsum[blockIdx.x] = sdata[255];
}

__global__ __launch_bounds__(256) void scan_bsums_kernel(int* __restrict__ bsum,
                                                         int M) {
  __shared__ int sd[256];
  const int tid = threadIdx.x;
  const int v = (tid < M) ? bsum[tid] : 0;
  sd[tid] = v;
  __syncthreads();
#pragma unroll
  for (int off = 1; off < 256; off <<= 1) {
    int t = (tid >= off) ? sd[tid - off] : 0;
    __syncthreads();
    sd[tid] += t;
    __syncthreads();
  }
  if (tid < M) bsum[tid] = sd[tid] - v;
}

__global__ __launch_bounds__(256) void scan_add_kernel(
    int* __restrict__ out, const int* __restrict__ bsum, int N) {
  const int i = blockIdx.x * 256 + threadIdx.x;
  if (i < N) out[i] += bsum[i / kScanTile];
  if (i == 0) out[N] = 2 * kNNZ;
}

__global__ __launch_bounds__(256) void scatter_kernel(
    const int* __restrict__ rows, const int* __restrict__ cols,
    const float* __restrict__ vals, int* __restrict__ cur,
    Edge* __restrict__ edges) {
  const int e = blockIdx.x * 256 + threadIdx.x;
  if (e >= kNNZ) return;
  const int r = rows[e];
  const int c = cols[e];
  const float v = vals[e];
  const int p = atomicAdd(&cur[r], 1);
  *(int2*)&edges[p] = make_int2(c, __float_as_int(v));
  const int q = atomicAdd(&cur[kNU + c], 1);
  *(int2*)&edges[q] = make_int2(r, __float_as_int(v));
}

// ---------------------------------------------------------------------------
// Gather SpMM (bf16 src/dst, f32 accumulate). 16-lane subgroup per output
// row: each lane holds 8 feats (uint4 = bf16x8), 4 rows per wave -> 4x the
// loads in flight vs one-row-per-wave. Dual variant shares edge traversal.
// ---------------------------------------------------------------------------
__global__ __launch_bounds__(256) void spmm_g1_kernel(
    uint* __restrict__ dst, const uint* __restrict__ src,
    const int* __restrict__ ptr, const Edge* __restrict__ edges, int N) {
  const int sub = threadIdx.x >> 4;
  const int l16 = threadIdx.x & 15;
  const int n = blockIdx.x * 16 + sub;
  if (n >= N) return;
  const int off = l16 << 2;
  int e = ptr[n];
  const int e1 = ptr[n + 1];
  float acc[8] = {0.f, 0.f, 0.f, 0.f, 0.f, 0.f, 0.f, 0.f};
  for (; e + 2 <= e1; e += 2) {
    const Edge r0 = edges[e];
    const Edge r1 = edges[e + 1];
    const uint4 s0 = *(const uint4*)(src + (size_t)r0.idx * kDH2 + off);
    const uint4 s1 = *(const uint4*)(src + (size_t)r1.idx * kDH2 + off);
    fma8(acc, s0, r0.val);
    fma8(acc, s1, r1.val);
  }
  if (e < e1) {
    const Edge r = edges[e];
    const uint4 s = *(const uint4*)(src + (size_t)r.idx * kDH2 + off);
    fma8(acc, s, r.val);
  }
  *(uint4*)(dst + (size_t)n * kDH2 + off) = pack8(acc);
}

__global__ __launch_bounds__(256) void spmm_g2_kernel(
    uint* __restrict__ dstA, const uint* __restrict__ srcA,
    uint* __restrict__ dstB, const uint* __restrict__ srcB,
    const int* __restrict__ ptr, const Edge* __restrict__ edges, int N) {
  const int sub = threadIdx.x >> 4;
  const int l16 = threadIdx.x & 15;
  const int n = blockIdx.x * 16 + sub;
  if (n >= N) return;
  const int off = l16 << 2;
  int e = ptr[n];
  const int e1 = ptr[n + 1];
  float aA[8] = {0.f, 0.f, 0.f, 0.f, 0.f, 0.f, 0.f, 0.f};
  float aB[8] = {0.f, 0.f, 0.f, 0.f, 0.f, 0.f, 0.f, 0.f};
  for (; e + 2 <= e1; e += 2) {
    const Edge r0 = edges[e];
    const Edge r1 = edges[e + 1];
    const uint4 a0 = *(const uint4*)(srcA + (size_t)r0.idx * kDH2 + off);
    const uint4 b0 = *(const uint4*)(srcB + (size_t)r0.idx * kDH2 + off);
    const uint4 a1 = *(const uint4*)(srcA + (size_t)r1.idx * kDH2 + off);
    const uint4 b1 = *(const uint4*)(srcB + (size_t)r1.idx * kDH2 + off);
    fma8(aA, a0, r0.val);
    fma8(aB, b0, r0.val);
    fma8(aA, a1, r1.val);
    fma8(aB, b1, r1.val);
  }
  if (e < e1) {
    const Edge r = edges[e];
    const uint4 a = *(const uint4*)(srcA + (size_t)r.idx * kDH2 + off);
    const uint4 b = *(const uint4*)(srcB + (size_t)r.idx * kDH2 + off);
    fma8(aA, a, r.val);
    fma8(aB, b, r.val);
  }
  *(uint4*)(dstA + (size_t)n * kDH2 + off) = pack8(aA);
  *(uint4*)(dstB + (size_t)n * kDH2 + off) = pack8(aB);
}

// ---------------------------------------------------------------------------
// Fused FC (bias-free) + LayerNorm, bf16 in/out, f32 math.
// ---------------------------------------------------------------------------
constexpr int kFclnRows = 8;
constexpr int kWPad = 132;

__global__ __launch_bounds__(256) void fcln_kernel(
    const uint* __restrict__ X, const float* __restrict__ W,
    const float* __restrict__ g, const float* __restrict__ b,
    uint* __restrict__ out, int N) {
  __shared__ float Wt[kDH * kWPad];
  __shared__ float Xl[kFclnRows][kDH];
  const int tid = threadIdx.x;
  for (int idx = tid; idx < kDH * kDH; idx += 256) {
    const int d = idx >> 7, k = idx & 127;
    Wt[k * kWPad + d] = W[idx];
  }
  const int row0 = blockIdx.x * kFclnRows;
  const int r = tid >> 5;
  const int l = tid & 31;
  {
    const int n = row0 + r;
    uint2 xv = make_uint2(0u, 0u);
    if (n < N) xv = *(const uint2*)(X + (size_t)n * kDH2 + l * 2);
    const float2 p0 = bf2f(xv.x);
    const float2 p1 = bf2f(xv.y);
    Xl[r][l * 4 + 0] = p0.x;
    Xl[r][l * 4 + 1] = p0.y;
    Xl[r][l * 4 + 2] = p1.x;
    Xl[r][l * 4 + 3] = p1.y;
  }
  __syncthreads();
  float4 acc = make_float4(0.f, 0.f, 0.f, 0.f);
  const int d0 = l * 4;
#pragma unroll 4
  for (int k = 0; k < kDH; ++k) {
    const float x = Xl[r][k];
    const float4 w = *(const float4*)(&Wt[k * kWPad + d0]);
    acc.x = fmaf(x, w.x, acc.x);
    acc.y = fmaf(x, w.y, acc.y);
    acc.z = fmaf(x, w.z, acc.z);
    acc.w = fmaf(x, w.w, acc.w);
  }
  float s = acc.x + acc.y + acc.z + acc.w;
  float sq = acc.x * acc.x + acc.y * acc.y + acc.z * acc.z + acc.w * acc.w;
#pragma unroll
  for (int m = 16; m >= 1; m >>= 1) {
    s += __shfl_xor(s, m, 32);
    sq += __shfl_xor(sq, m, 32);
  }
  const float mu = s * (1.f / kDH);
  const float var = sq * (1.f / kDH) - mu * mu;
  const float rs = 1.f / sqrtf(var + kEps);
  const int n = row0 + r;
  if (n < N) {
    const float4 gg = *(const float4*)(g + d0);
    const float4 bb = *(const float4*)(b + d0);
    float2 o0, o1;
    o0.x = (acc.x - mu) * rs * gg.x + bb.x;
    o0.y = (acc.y - mu) * rs * gg.y + bb.y;
    o1.x = (acc.z - mu) * rs * gg.z + bb.z;
    o1.y = (acc.w - mu) * rs * gg.w + bb.w;
    *(uint2*)(out + (size_t)n * kDH2 + l * 2) = make_uint2(f2bf(o0), f2bf(o1));
  }
}

// ---------------------------------------------------------------------------
// h = leaky(LN(T)*g+b); upd(bf16) += h; acc(f32, d_out) += h
// ---------------------------------------------------------------------------
__global__ __launch_bounds__(256) void leaky_ln_kernel(
    const uint* __restrict__ T, const float* __restrict__ g,
    const float* __restrict__ b, uint* __restrict__ upd,
    float* __restrict__ acc, int N) {
  const int wid = threadIdx.x >> 6;
  const int lane = threadIdx.x & 63;
  const int n = blockIdx.x * 4 + wid;
  if (n >= N) return;
  const float2 v = bf2f(T[(size_t)n * kDH2 + lane]);
  float s = v.x + v.y;
  float sq = v.x * v.x + v.y * v.y;
#pragma unroll
  for (int m = 32; m >= 1; m >>= 1) {
    s += __shfl_xor(s, m, 64);
    sq += __shfl_xor(sq, m, 64);
  }
  const float mu = s * (1.f / kDH);
  const float var = sq * (1.f / kDH) - mu * mu;
  const float rs = 1.f / sqrtf(var + kEps);
  const int d = lane * 2;
  const float2 gg = *(const float2*)(g + d);
  const float2 bb = *(const float2*)(b + d);
  float hx = (v.x - mu) * rs * gg.x + bb.x;
  float hy = (v.y - mu) * rs * gg.y + bb.y;
  hx = hx > 0.f ? hx : kSlope * hx;
  hy = hy > 0.f ? hy : kSlope * hy;
  float2 uv = bf2f(upd[(size_t)n * kDH2 + lane]);
  uv.x += hx;
  uv.y += hy;
  upd[(size_t)n * kDH2 + lane] = f2bf(uv);
  float2 av = *(const float2*)(acc + (size_t)n * kDH + d);
  av.x += hx;
  av.y += hy;
  *(float2*)(acc + (size_t)n * kDH + d) = av;
}

__global__ __launch_bounds__(256) void scale_kernel(float* __restrict__ p,
                                                    float sc, int n4) {
  const int gid = blockIdx.x * 256 + threadIdx.x;
  if (gid < n4) {
    float4 v = ((float4*)p)[gid];
    v.x *= sc; v.y *= sc; v.z *= sc; v.w *= sc;
    ((float4*)p)[gid] = v;
  }
}

}  // namespace

extern "C" void kernel_launch(void* const* d_in, const int* in_sizes, int n_in,
                              void* d_out, int out_size, void* d_ws,
                              size_t ws_size, hipStream_t stream) {
  const float* emb    = (const float*)d_in[0];
  const float* fc_u_w = (const float*)d_in[1];
  const float* fc_u_b = (const float*)d_in[2];
  const float* fc_i_w = (const float*)d_in[3];
  const float* fc_i_b = (const float*)d_in[4];
  const float* vals   = (const float*)d_in[5];
  const float* Wu     = (const float*)d_in[6];
  const float* ln1g_u = (const float*)d_in[7];
  const float* ln1b_u = (const float*)d_in[8];
  const float* ln2g_u = (const float*)d_in[9];
  const float* ln2b_u = (const float*)d_in[10];
  const float* Wi     = (const float*)d_in[11];
  const float* ln1g_i = (const float*)d_in[12];
  const float* ln1b_i = (const float*)d_in[13];
  const float* ln2g_i = (const float*)d_in[14];
  const float* ln2b_i = (const float*)d_in[15];
  const int*   rows   = (const int*)d_in[16];
  const int*   cols   = (const int*)d_in[17];
  float* out = (float*)d_out;

  // Workspace: bufU | bufI | P | Q | R | edges[2*NNZ] | cnt | ptr | cur | bsum
  uint* bufU = (uint*)d_ws;
  uint* bufI = bufU + (size_t)kNU * kDH2;
  uint* P    = bufI + (size_t)kNI * kDH2;
  uint* Q    = P + (size_t)kNU * kDH2;
  uint* R    = Q + (size_t)kNU * kDH2;
  Edge* edges = (Edge*)(R + (size_t)kNU * kDH2);
  int*  cnt  = (int*)(edges + (size_t)2 * kNNZ);
  int*  ptr  = cnt + kNSeg;
  int*  cur  = ptr + kNSeg + 1;
  int*  bsum = cur + kNSeg + 1;

  const int egrid = (kNNZ + 255) / 256;
  const int gridU = (kNU + 15) / 16;
  const int gridI = (kNI + 15) / 16;
  const int lgridU = (kNU + 3) / 4;
  const int lgridI = (kNI + 3) / 4;
  const int fgridU = (kNU + kFclnRows - 1) / kFclnRows;
  const int fgridI = (kNI + kFclnRows - 1) / kFclnRows;

  // ---- adjacency build ----
  hipMemsetAsync(cnt, 0, (size_t)kNSeg * sizeof(int), stream);
  hist_kernel<<<egrid, 256, 0, stream>>>(rows, cols, cnt);
  scan_partial_kernel<<<kScanBlocks, 256, 0, stream>>>(cnt, ptr, bsum, kNSeg);
  scan_bsums_kernel<<<1, 256, 0, stream>>>(bsum, kScanBlocks);
  scan_add_kernel<<<(kNSeg + 255) / 256, 256, 0, stream>>>(ptr, bsum, kNSeg);
  hipMemcpyAsync(cur, ptr, (size_t)(kNSeg + 1) * sizeof(int),
                 hipMemcpyDeviceToDevice, stream);
  scatter_kernel<<<egrid, 256, 0, stream>>>(rows, cols, vals, cur, edges);

  // ---- input FC ----
  fc_in_kernel<<<kNU + kNI, 128, 0, stream>>>(emb, fc_u_w, fc_u_b, fc_i_w,
                                              fc_i_b, bufU, bufI, out);

  // ---- layer 0 ----
  spmm_g1_kernel<<<gridI, 256, 0, stream>>>(P, bufU, ptr + kNU, edges, kNI);
  fcln_kernel<<<fgridI, 256, 0, stream>>>(P, Wu, ln1g_u, ln1b_u, Q, kNI);
  spmm_g2_kernel<<<gridU, 256, 0, stream>>>(P, Q, R, bufI, ptr, edges, kNU);
  leaky_ln_kernel<<<lgridU, 256, 0, stream>>>(P, ln2g_u, ln2b_u, bufU, out,
                                              kNU);
  fcln_kernel<<<fgridU, 256, 0, stream>>>(R, Wi, ln1g_i, ln1b_i, Q, kNU);
  spmm_g2_kernel<<<gridI, 256, 0, stream>>>(P, Q, R, bufU, ptr + kNU, edges,
                                            kNI);
  leaky_ln_kernel<<<lgridI, 256, 0, stream>>>(P, ln2g_i, ln2b_i, bufI,
                                              out + (size_t)kNU * kDH, kNI);
  // ---- layer 1 ----
  fcln_kernel<<<fgridI, 256, 0, stream>>>(R, Wu + kDH * kDH, ln1g_u + kDH,
                                          ln1b_u + kDH, Q, kNI);
  spmm_g2_kernel<<<gridU, 256, 0, stream>>>(P, Q, R, bufI, ptr, edges, kNU);
  leaky_ln_kernel<<<lgridU, 256, 0, stream>>>(P, ln2g_u + kDH, ln2b_u + kDH,
                                              bufU, out, kNU);
  fcln_kernel<<<fgridU, 256, 0, stream>>>(R, Wi + kDH * kDH, ln1g_i + kDH,
                                          ln1b_i + kDH, Q, kNU);
  spmm_g1_kernel<<<gridI, 256, 0, stream>>>(P, Q, ptr + kNU, edges, kNI);
  leaky_ln_kernel<<<lgridI, 256, 0, stream>>>(P, ln2g_i + kDH, ln2b_i + kDH,
                                              bufI, out + (size_t)kNU * kDH,
                                              kNI);

  const int n4 = (kNU + kNI) * kDH / 4;
  scale_kernel<<<(n4 + 255) / 256, 256, 0, stream>>>(out, 1.f / 3.f, n4);
}